// Round 10
// baseline (390.765 us; speedup 1.0000x reference)
//
#include <hip/hip_runtime.h>
#include <hip/hip_bf16.h>
#include <cstddef>

#define GN 50000
#define GE 800000
#define GH 4
#define GD 32
#define SLOPE 0.2f
#define LOG2E 1.4426950408889634f

typedef unsigned short ushort_t;
typedef unsigned int uint_t;
using short8 = __attribute__((ext_vector_type(8))) short;
using float4v = __attribute__((ext_vector_type(4))) float;

__device__ __forceinline__ ushort_t f2bf(float f) {
    union { float f; uint_t u; } v; v.f = f;
    uint_t r = v.u + 0x7fff + ((v.u >> 16) & 1);   // RNE
    return (ushort_t)(r >> 16);
}
__device__ __forceinline__ float bflo(uint_t u) { return __uint_as_float(u << 16); }
__device__ __forceinline__ float bfhi(uint_t u) { return __uint_as_float(u & 0xffff0000u); }
__device__ __forceinline__ float bfu(ushort_t u) { return __uint_as_float((uint_t)u << 16); }

// v_cvt_pk_bf16_f32: D[15:0]=bf16(lo), D[31:16]=bf16(hi), RNE — same rounding as f2bf
__device__ __forceinline__ uint_t cvt_pk_bf16(float lo, float hi) {
    uint_t r;
    asm("v_cvt_pk_bf16_f32 %0, %1, %2" : "=v"(r) : "v"(lo), "v"(hi));
    return r;
}

#if __has_builtin(__builtin_amdgcn_exp2f)
#define EXP2F(x) __builtin_amdgcn_exp2f(x)
#else
#define EXP2F(x) exp2f(x)
#endif

// broadcast within each 8-lane group (and_mask=0x18 keeps bits 3,4; or_mask=k)
#define SWZ_B(v, imm) __uint_as_float((uint_t)__builtin_amdgcn_ds_swizzle((int)__float_as_uint(v), (imm)))

// path-interleaved row slot: storage row a (0..2N) -> slot (path0/path1 interleaved)
__device__ __forceinline__ int slotmap(int a) {
    return (a < GN) ? (a << 1) : (((a - GN) << 1) | 1);
}

// extended-N GEMM geometry: 128 feature cols + 8 attn cols (el h0..3, er h0..3) + pad
#define NEXT 144
#define WSTRIDE (NEXT * 128)

// ---------------- scans ----------------
__global__ void k_scan1(const int* __restrict__ deg, int* __restrict__ row_ptr,
                        int* __restrict__ partials, int n) {
    __shared__ int s[256];
    int t = threadIdx.x;
    int i = blockIdx.x * 256 + t;
    int v = (i < n) ? deg[i] : 0;
    s[t] = v;
    __syncthreads();
    for (int off = 1; off < 256; off <<= 1) {
        int add = (t >= off) ? s[t - off] : 0;
        __syncthreads();
        s[t] += add;
        __syncthreads();
    }
    if (i < n) row_ptr[i] = s[t] - v;
    if (t == 255) partials[blockIdx.x] = s[255];
}

__global__ void k_scan2(int* __restrict__ partials, int nb) {
    __shared__ int s[256];
    int t = threadIdx.x;
    int v = (t < nb) ? partials[t] : 0;
    s[t] = v;
    __syncthreads();
    for (int off = 1; off < 256; off <<= 1) {
        int add = (t >= off) ? s[t - off] : 0;
        __syncthreads();
        s[t] += add;
        __syncthreads();
    }
    if (t < nb) partials[t] = s[t] - v;
}

__global__ void k_scan3(int* __restrict__ row_ptr, int* __restrict__ wpos,
                        const int* __restrict__ partials, int n, int E) {
    int i = blockIdx.x * 256 + threadIdx.x;
    if (i < n) {
        int rp = row_ptr[i] + partials[i >> 8];
        row_ptr[i] = rp;
        wpos[i] = rp;
        if (i == 0) row_ptr[n] = E;
    }
}

// ---------------- FUSED: weight convert (blocks [0,cvtb)) + hist (rest) ----------------
// The two are independent; fusing lets the 800k-atomic scatter overlap the convert.
// wbt layout [2][NEXT][128]: n<128 = W^T; n=128+h = W·al_h ×LOG2E; n=132+h = W·ar_h ×LOG2E.
__global__ __launch_bounds__(256) void k_cvt_hist(
    const float* __restrict__ W0, const float* __restrict__ W1,
    const float* __restrict__ Wout,
    const float* __restrict__ al0, const float* __restrict__ ar0,
    const float* __restrict__ al1, const float* __restrict__ ar1,
    ushort_t* __restrict__ wbt, ushort_t* __restrict__ woutb,
    const int* __restrict__ dst, int* __restrict__ wpos, int cvtb, int E) {
    if ((int)blockIdx.x >= cvtb) {
        int i = (blockIdx.x - cvtb) * 256 + threadIdx.x;
        if (i < E) atomicAdd(&wpos[dst[i]], 1);
        return;
    }
    int t = blockIdx.x * 256 + threadIdx.x;
    if (t < 2 * WSTRIDE) {
        int m = t / WSTRIDE;
        int o = t % WSTRIDE;
        int n = o >> 7, k = o & 127;
        const float* W = m ? W1 : W0;
        float v;
        if (n < 128) {
            v = W[k * 128 + n];
        } else if (n < 136) {
            int j = n - 128;
            int h = j & 3;
            const float* a = (j < 4) ? (m ? al1 : al0) : (m ? ar1 : ar0);
            float s = 0.f;
#pragma unroll 8
            for (int d = 0; d < 32; d++) s += W[k * 128 + h * 32 + d] * a[h * 32 + d];
            v = s * LOG2E;
        } else {
            v = 0.f;
        }
        wbt[t] = f2bf(v);
    } else {
        int u = t - 2 * WSTRIDE;      // 0..6143
        if (u < 48 * 128) {
            int n = u >> 7, k = u & 127;
            float w = (n < 40) ? Wout[k * 40 + n] : 0.f;
            ushort_t h = f2bf(w);
            woutb[u] = h;
            woutb[48 * 128 + u] = f2bf(w - bfu(h));
        }
    }
}

// C-store (interleaved row layout): pack row pairs with v_cvt_pk_bf16_f32;
// 9th tile = el/er direct fp32 stores (already LOG2E-scaled by the weights).
__device__ __forceinline__ void store_c_ext(ushort_t* __restrict__ Cb,
                                            float* __restrict__ el,
                                            float* __restrict__ er,
                                            const float4v acc[2][9],
                                            int r0, int quad, int col, int M) {
#pragma unroll
    for (int rt = 0; rt < 2; rt++)
#pragma unroll
        for (int nt = 0; nt < 8; nt++) {
            int rb = r0 + rt * 16 + quad * 4;
            int c = nt * 16 + col;
            uint_t p01 = cvt_pk_bf16(acc[rt][nt][0], acc[rt][nt][1]);
            uint_t p23 = cvt_pk_bf16(acc[rt][nt][2], acc[rt][nt][3]);
            if (rb + 0 < M) Cb[(size_t)slotmap(rb + 0) * 128 + c] = (ushort_t)p01;
            if (rb + 1 < M) Cb[(size_t)slotmap(rb + 1) * 128 + c] = (ushort_t)(p01 >> 16);
            if (rb + 2 < M) Cb[(size_t)slotmap(rb + 2) * 128 + c] = (ushort_t)p23;
            if (rb + 3 < M) Cb[(size_t)slotmap(rb + 3) * 128 + c] = (ushort_t)(p23 >> 16);
        }
    // attn columns: col<4 -> el head col; col in 4..7 -> er head col-4
    if (col < 8) {
        float* dstp = (col < 4) ? el : er;
        int h = col & 3;
#pragma unroll
        for (int rt = 0; rt < 2; rt++)
#pragma unroll
            for (int r = 0; r < 4; r++) {
                int row = r0 + rt * 16 + quad * 4 + r;
                if (row < M) dstp[slotmap(row) * 4 + h] = acc[rt][8][r];
            }
    }
}

// ---------------- FUSED: MFMA GEMM layer-1 (blocks [0,gblocks)) + csr fill (rest) ----
// Both ready after scan3 (gemm needs only cvt output). gemm blocks first: they
// grab CUs; fill's scatter backfills. Fill blocks pay the static 38KB LDS
// (4 blocks/CU = 16 waves/CU — fine for a latency-bound scatter).
__global__ __launch_bounds__(256) void k_gemm32_fill(
    const float* __restrict__ A0, const float* __restrict__ A1,
    const ushort_t* __restrict__ WbT,
    ushort_t* __restrict__ Cb, float* __restrict__ el, float* __restrict__ er,
    int M, int gblocks,
    const int* __restrict__ src, const int* __restrict__ dst,
    int* __restrict__ wpos, int* __restrict__ csr_src, int E) {
    __shared__ ushort_t Bs[NEXT][136];
    if ((int)blockIdx.x >= gblocks) {
        int i = (blockIdx.x - gblocks) * 256 + threadIdx.x;
        if (i < E) {
            int p = atomicAdd(&wpos[dst[i]], 1);
            csr_src[p] = src[i];
        }
        return;
    }
    int tid = threadIdx.x;
    for (int i = tid; i < NEXT * 16; i += 256) {
        int n = i >> 4;
        int kc = (i & 15) << 3;
        *(short8*)&Bs[n][kc] = *(const short8*)&WbT[n * 128 + kc];
    }
    __syncthreads();
    int wid = tid >> 6, lane = tid & 63;
    int r0 = blockIdx.x * 128 + wid * 32;
    int col = lane & 15, quad = lane >> 4;
    float4v acc[2][9];
#pragma unroll
    for (int rt = 0; rt < 2; rt++)
#pragma unroll
        for (int t = 0; t < 9; t++) acc[rt][t] = (float4v){0.f, 0.f, 0.f, 0.f};
    int ar_[2] = {r0 + col, r0 + 16 + col};
    const float* Ap[2];
#pragma unroll
    for (int rt = 0; rt < 2; rt++) {
        int a = ar_[rt];
        Ap[rt] = (a < M) ? ((a < GN) ? (A0 + (size_t)a * 128)
                                     : (A1 + (size_t)(a - GN) * 128)) : nullptr;
    }
#pragma unroll
    for (int ks = 0; ks < 4; ks++) {
        short8 af[2];
#pragma unroll
        for (int rt = 0; rt < 2; rt++) {
            af[rt] = (short8){};
            if (Ap[rt]) {
                float4 v0 = *(const float4*)&Ap[rt][ks * 32 + quad * 8];
                float4 v1 = *(const float4*)&Ap[rt][ks * 32 + quad * 8 + 4];
                union { short8 s; uint_t u[4]; } cv;
                cv.u[0] = cvt_pk_bf16(v0.x, v0.y);
                cv.u[1] = cvt_pk_bf16(v0.z, v0.w);
                cv.u[2] = cvt_pk_bf16(v1.x, v1.y);
                cv.u[3] = cvt_pk_bf16(v1.z, v1.w);
                af[rt] = cv.s;
            }
        }
#pragma unroll
        for (int nt = 0; nt < 9; nt++) {
            short8 bf = *(const short8*)&Bs[nt * 16 + col][ks * 32 + quad * 8];
            acc[0][nt] = __builtin_amdgcn_mfma_f32_16x16x32_bf16(af[0], bf, acc[0][nt], 0, 0, 0);
            acc[1][nt] = __builtin_amdgcn_mfma_f32_16x16x32_bf16(af[1], bf, acc[1][nt], 0, 0, 0);
        }
    }
    store_c_ext(Cb, el, er, acc, r0, quad, col, M);
}

// ---------------- MFMA GEMM (bf16 A interleaved, layer 2), N=144 ----------------
__global__ __launch_bounds__(256) void gemm_mfma(const ushort_t* __restrict__ A,
                                                 const ushort_t* __restrict__ WbT,
                                                 ushort_t* __restrict__ Cb,
                                                 float* __restrict__ el,
                                                 float* __restrict__ er, int M) {
    __shared__ ushort_t Bs[NEXT][136];
    int tid = threadIdx.x;
    for (int i = tid; i < NEXT * 16; i += 256) {
        int n = i >> 4;
        int kc = (i & 15) << 3;
        *(short8*)&Bs[n][kc] = *(const short8*)&WbT[n * 128 + kc];
    }
    __syncthreads();
    int wid = tid >> 6, lane = tid & 63;
    int r0 = blockIdx.x * 128 + wid * 32;
    int col = lane & 15, quad = lane >> 4;
    float4v acc[2][9];
#pragma unroll
    for (int rt = 0; rt < 2; rt++)
#pragma unroll
        for (int t = 0; t < 9; t++) acc[rt][t] = (float4v){0.f, 0.f, 0.f, 0.f};
    int ar_[2] = {r0 + col, r0 + 16 + col};
    const ushort_t* Ap[2];
#pragma unroll
    for (int rt = 0; rt < 2; rt++) {
        int a = ar_[rt];
        Ap[rt] = (a < M) ? (A + (size_t)slotmap(a) * 128) : nullptr;
    }
#pragma unroll
    for (int ks = 0; ks < 4; ks++) {
        short8 af[2];
#pragma unroll
        for (int rt = 0; rt < 2; rt++) {
            af[rt] = (short8){};
            if (Ap[rt]) af[rt] = *(const short8*)&Ap[rt][ks * 32 + quad * 8];
        }
#pragma unroll
        for (int nt = 0; nt < 9; nt++) {
            short8 bf = *(const short8*)&Bs[nt * 16 + col][ks * 32 + quad * 8];
            acc[0][nt] = __builtin_amdgcn_mfma_f32_16x16x32_bf16(af[0], bf, acc[0][nt], 0, 0, 0);
            acc[1][nt] = __builtin_amdgcn_mfma_f32_16x16x32_bf16(af[1], bf, acc[1][nt], 0, 0, 0);
        }
    }
    store_c_ext(Cb, el, er, acc, r0, quad, col, M);
}

// ---- shared agg gather core (unchanged from measured-best: one node/wave,
// 16-edge masked blocks, gathered el, dedup'd exp, ds_swizzle broadcast) ----
__device__ __forceinline__ void agg_core(
    const ushort_t* __restrict__ featb, const float* __restrict__ el, float ern,
    const int* __restrict__ csr_src, int base, int deg, uint_t eo, uint_t fofs,
    int lk, float& v0, float& v1, float& v2, float& v3) {
    if (deg <= 0) { v0 = v1 = v2 = v3 = 0.f; return; }
    float a0 = 0.f, a1 = 0.f, a2 = 0.f, a3 = 0.f, ss = 0.f;
    int nblk = (deg + 15) >> 4;
    int e1 = base + deg - 1;
    int jb = base;
    int s[16], t[16];
#pragma unroll
    for (int k = 0; k < 16; k++) s[k] = csr_src[min(jb + k, e1)];
    float elA = el[(uint_t)csr_src[min(jb + lk, e1)] * 8u + eo];
    float elB = el[(uint_t)csr_src[min(jb + lk + 8, e1)] * 8u + eo];
    for (int b = 0;;) {
        int rem = deg - (b << 4);
        uint2 f[16];
#pragma unroll
        for (int k = 0; k < 16; k++)
            f[k] = *(const uint2*)&featb[(uint_t)s[k] * 256u + fofs];
        bool more = (b + 1) < nblk;
        float elA2 = 0.f, elB2 = 0.f;
        if (more) {
            int nj = jb + 16;
#pragma unroll
            for (int k = 0; k < 16; k++) t[k] = csr_src[min(nj + k, e1)];
            elA2 = el[(uint_t)csr_src[min(nj + lk, e1)] * 8u + eo];
            elB2 = el[(uint_t)csr_src[min(nj + lk + 8, e1)] * 8u + eo];
        }
        float eA = elA + ern; eA = fmaxf(eA, SLOPE * eA);
        float eB = elB + ern; eB = fmaxf(eB, SLOPE * eB);
        float wA = (lk < rem) ? EXP2F(eA) : 0.f;
        float wB = (lk + 8 < rem) ? EXP2F(eB) : 0.f;
        float wv[16];
        wv[0]  = SWZ_B(wA, 0x018); wv[1]  = SWZ_B(wA, 0x038);
        wv[2]  = SWZ_B(wA, 0x058); wv[3]  = SWZ_B(wA, 0x078);
        wv[4]  = SWZ_B(wA, 0x098); wv[5]  = SWZ_B(wA, 0x0B8);
        wv[6]  = SWZ_B(wA, 0x0D8); wv[7]  = SWZ_B(wA, 0x0F8);
        wv[8]  = SWZ_B(wB, 0x018); wv[9]  = SWZ_B(wB, 0x038);
        wv[10] = SWZ_B(wB, 0x058); wv[11] = SWZ_B(wB, 0x078);
        wv[12] = SWZ_B(wB, 0x098); wv[13] = SWZ_B(wB, 0x0B8);
        wv[14] = SWZ_B(wB, 0x0D8); wv[15] = SWZ_B(wB, 0x0F8);
#pragma unroll
        for (int k = 0; k < 16; k++) {
            float w = wv[k];
            ss += w;
            a0 += w * bflo(f[k].x);
            a1 += w * bfhi(f[k].x);
            a2 += w * bflo(f[k].y);
            a3 += w * bfhi(f[k].y);
        }
        if (!more) break;
        b++; jb += 16;
#pragma unroll
        for (int k = 0; k < 16; k++) s[k] = t[k];
        elA = elA2; elB = elB2;
    }
    float inv = 1.f / ss;
    v0 = a0 * inv; v1 = a1 * inv; v2 = a2 * inv; v3 = a3 * inv;
}

// ---------------- layer-1 aggregate: -> abuf (bf16, interleaved) ----------------
__global__ __launch_bounds__(512) void gat_agg_l1(
    const ushort_t* __restrict__ featb, const float* __restrict__ el,
    const float* __restrict__ er, const int* __restrict__ row_ptr,
    const int* __restrict__ csr_src, ushort_t* __restrict__ abuf) {
    int n = __builtin_amdgcn_readfirstlane(blockIdx.x * 8 + (threadIdx.x >> 6));
    if (n >= GN) return;
    int lane = threadIdx.x & 63;
    int half = lane >> 5;
    int q = lane & 31;
    int lk = lane & 7, q4 = q << 2;
    uint_t eo = (uint_t)(half * 4 + ((lane >> 3) & 3));
    uint_t fofs = (uint_t)(half * 128 + q4);
    float ern = er[(uint_t)n * 8u + eo];
    int base = row_ptr[n];
    int deg = row_ptr[n + 1] - base;
    float v0, v1, v2, v3;
    agg_core(featb, el, ern, csr_src, base, deg, eo, fofs, lk, v0, v1, v2, v3);
    v0 = v0 > 0.f ? v0 : __expf(v0) - 1.f;
    v1 = v1 > 0.f ? v1 : __expf(v1) - 1.f;
    v2 = v2 > 0.f ? v2 : __expf(v2) - 1.f;
    v3 = v3 > 0.f ? v3 : __expf(v3) - 1.f;
    size_t idx = ((size_t)(2 * n + half)) * 128 + q4;
    uint2 o;
    o.x = cvt_pk_bf16(v0, v1);
    o.y = cvt_pk_bf16(v2, v3);
    *(uint2*)&abuf[idx] = o;
}

// ---------------- layer-2 aggregate + residual + ELU + mixup + h write ----------------
__global__ __launch_bounds__(512) void gat_agg_l2(
    const ushort_t* __restrict__ featb, const float* __restrict__ el,
    const float* __restrict__ er, const int* __restrict__ row_ptr,
    const int* __restrict__ csr_src, const ushort_t* __restrict__ resid,
    const float* __restrict__ lamb, float* __restrict__ outh) {
    int tid = threadIdx.x;
    int n = __builtin_amdgcn_readfirstlane(blockIdx.x * 8 + (tid >> 6));
    if (n >= GN) return;
    int lane = tid & 63;
    int half = lane >> 5;
    int q = lane & 31;
    int lk = lane & 7, q4 = q << 2;
    uint_t eo = (uint_t)(half * 4 + ((lane >> 3) & 3));
    uint_t fofs = (uint_t)(half * 128 + q4);
    float ern = er[(uint_t)n * 8u + eo];
    int base = row_ptr[n];
    int deg = row_ptr[n + 1] - base;
    float v0, v1, v2, v3;
    agg_core(featb, el, ern, csr_src, base, deg, eo, fofs, lk, v0, v1, v2, v3);
    // residual (bf16, interleaved) + ELU
    size_t idx = ((size_t)(2 * n + half)) * 128 + q4;
    ushort4 r = *(const ushort4*)&resid[idx];
    v0 += bfu(r.x); v1 += bfu(r.y); v2 += bfu(r.z); v3 += bfu(r.w);
    v0 = v0 > 0.f ? v0 : __expf(v0) - 1.f;
    v1 = v1 > 0.f ? v1 : __expf(v1) - 1.f;
    v2 = v2 > 0.f ? v2 : __expf(v2) - 1.f;
    v3 = v3 > 0.f ? v3 : __expf(v3) - 1.f;
    // mixup across halves (partner lane = lane ^ 32)
    float p0 = __shfl_xor(v0, 32, 64);
    float p1 = __shfl_xor(v1, 32, 64);
    float p2 = __shfl_xor(v2, 32, 64);
    float p3 = __shfl_xor(v3, 32, 64);
    float lam = lamb[0];
    if (half == 0) {
        float m0 = lam * v0 + (1.f - lam) * p0;
        float m1 = lam * v1 + (1.f - lam) * p1;
        float m2 = lam * v2 + (1.f - lam) * p2;
        float m3 = lam * v3 + (1.f - lam) * p3;
        *(float4*)&outh[(size_t)n * 128 + q4] = make_float4(m0, m1, m2, m3);
    }
}

// ---------------- logits: H[N,128] (f32) x Wout[128,40] via 3-product bf16-split MFMA
__global__ __launch_bounds__(256) void k_logits(const float* __restrict__ Hf,
                                                const ushort_t* __restrict__ Wb,
                                                const float* __restrict__ bout,
                                                float* __restrict__ outlog) {
    __shared__ ushort_t Bh[48][136];
    __shared__ ushort_t Bl[48][136];
    int tid = threadIdx.x;
    for (int i = tid; i < 48 * 16; i += 256) {
        int n = i >> 4;
        int kc = (i & 15) << 3;
        *(short8*)&Bh[n][kc] = *(const short8*)&Wb[n * 128 + kc];
        *(short8*)&Bl[n][kc] = *(const short8*)&Wb[48 * 128 + n * 128 + kc];
    }
    __syncthreads();
    int wid = tid >> 6, lane = tid & 63;
    int r0 = blockIdx.x * 128 + wid * 32;
    int col = lane & 15, quad = lane >> 4;
    float4v acc[2][3];
#pragma unroll
    for (int rt = 0; rt < 2; rt++)
#pragma unroll
        for (int nt = 0; nt < 3; nt++) acc[rt][nt] = (float4v){0.f, 0.f, 0.f, 0.f};
    int ar_[2] = {r0 + col, r0 + 16 + col};
#pragma unroll
    for (int ks = 0; ks < 4; ks++) {
        short8 ah[2], alo[2];
#pragma unroll
        for (int rt = 0; rt < 2; rt++) {
            ah[rt] = (short8){};
            alo[rt] = (short8){};
            if (ar_[rt] < GN) {
                const float* p = Hf + (size_t)ar_[rt] * 128 + ks * 32 + quad * 8;
                float4 x = *(const float4*)p;
                float4 y = *(const float4*)(p + 4);
                union { short8 s; uint_t u[4]; } ch, cl;
                ch.u[0] = cvt_pk_bf16(x.x, x.y);
                ch.u[1] = cvt_pk_bf16(x.z, x.w);
                ch.u[2] = cvt_pk_bf16(y.x, y.y);
                ch.u[3] = cvt_pk_bf16(y.z, y.w);
                cl.u[0] = cvt_pk_bf16(x.x - bflo(ch.u[0]), x.y - bfhi(ch.u[0]));
                cl.u[1] = cvt_pk_bf16(x.z - bflo(ch.u[1]), x.w - bfhi(ch.u[1]));
                cl.u[2] = cvt_pk_bf16(y.x - bflo(ch.u[2]), y.y - bfhi(ch.u[2]));
                cl.u[3] = cvt_pk_bf16(y.z - bflo(ch.u[3]), y.w - bfhi(ch.u[3]));
                ah[rt] = ch.s;
                alo[rt] = cl.s;
            }
        }
#pragma unroll
        for (int nt = 0; nt < 3; nt++) {
            short8 bh = *(const short8*)&Bh[nt * 16 + col][ks * 32 + quad * 8];
            short8 bl = *(const short8*)&Bl[nt * 16 + col][ks * 32 + quad * 8];
#pragma unroll
            for (int rt = 0; rt < 2; rt++) {
                acc[rt][nt] = __builtin_amdgcn_mfma_f32_16x16x32_bf16(ah[rt], bh, acc[rt][nt], 0, 0, 0);
                acc[rt][nt] = __builtin_amdgcn_mfma_f32_16x16x32_bf16(alo[rt], bh, acc[rt][nt], 0, 0, 0);
                acc[rt][nt] = __builtin_amdgcn_mfma_f32_16x16x32_bf16(ah[rt], bl, acc[rt][nt], 0, 0, 0);
            }
        }
    }
#pragma unroll
    for (int nt = 0; nt < 3; nt++) {
        int c = nt * 16 + col;
        if (c < 40) {
            float bv = bout[c];
#pragma unroll
            for (int rt = 0; rt < 2; rt++)
#pragma unroll
                for (int r = 0; r < 4; r++) {
                    int row = r0 + rt * 16 + quad * 4 + r;
                    if (row < GN) outlog[(size_t)row * 40 + c] = acc[rt][nt][r] + bv;
                }
        }
    }
}

extern "C" void kernel_launch(void* const* d_in, const int* in_sizes, int n_in,
                              void* d_out, int out_size, void* d_ws, size_t ws_size,
                              hipStream_t stream) {
    const float* inputs = (const float*)d_in[0];
    const float* target = (const float*)d_in[1];
    const float* lamb   = (const float*)d_in[2];
    const float* W0     = (const float*)d_in[3];
    const float* al0    = (const float*)d_in[4];
    const float* ar0    = (const float*)d_in[5];
    const float* W1     = (const float*)d_in[6];
    const float* al1    = (const float*)d_in[7];
    const float* ar1    = (const float*)d_in[8];
    const float* Wout   = (const float*)d_in[9];
    const float* bout   = (const float*)d_in[10];
    const int*   src    = (const int*)d_in[11];
    const int*   dst    = (const int*)d_in[12];

    float* out = (float*)d_out;
    float* outh = out;                          // [N,128]
    float* outlog = out + (size_t)GN * 128;     // [N,40]

    const int NP = 2 * GN;
    // workspace layout (featb/abuf/el/er are path-INTERLEAVED: slot = 2n+half)
    ushort_t* featb = (ushort_t*)d_ws;                    // [2N,128] bf16
    ushort_t* abuf  = featb + (size_t)NP * 128;           // [2N,128] bf16 (layer1 out / resid)
    float* el = (float*)(abuf + (size_t)NP * 128);        // [2N,4]  (pre-scaled by LOG2E)
    float* er = el + (size_t)NP * GH;                     // [2N,4]  (pre-scaled by LOG2E)
    ushort_t* wbt = (ushort_t*)(er + (size_t)NP * GH);    // [2][144][128] bf16 (ext cols)
    int* row_ptr  = (int*)(wbt + 2 * WSTRIDE);            // N+1
    int* wpos     = row_ptr + (GN + 1);                   // N
    int* csr_src  = wpos + GN;                            // E (+pad)
    int* partials = csr_src + GE + 16;                    // 256
    ushort_t* woutb = (ushort_t*)(partials + 256);        // [2][48][128] bf16 hi/lo

    const int nb = (GN + 255) / 256;
    const int eb = (GE + 255) / 256;
    const int gblocks = (NP + 127) / 128;
    const int aggblocks = (GN + 7) / 8;       // one node per wave, 8 waves/block
    const int lblocks = (GN + 127) / 128;
    const int cvtblocks = (2 * WSTRIDE + 48 * 128 + 255) / 256;

    // ---- stage 1: weight convert ∥ degree histogram (independent chains fused) ----
    hipMemsetAsync(wpos, 0, GN * sizeof(int), stream);
    k_cvt_hist<<<cvtblocks + eb, 256, 0, stream>>>(W0, W1, Wout, al0, ar0, al1, ar1,
                                                   wbt, woutb, dst, wpos,
                                                   cvtblocks, GE);

    // ---- scans (CSR prefix) ----
    k_scan1<<<nb, 256, 0, stream>>>(wpos, row_ptr, partials, GN);
    k_scan2<<<1, 256, 0, stream>>>(partials, nb);
    k_scan3<<<nb, 256, 0, stream>>>(row_ptr, wpos, partials, GN, GE);

    // ---- stage 2: layer-1 GEMM ∥ csr fill (independent after scan3) ----
    k_gemm32_fill<<<gblocks + eb, 256, 0, stream>>>(inputs, target, wbt,
                                                    featb, el, er, NP, gblocks,
                                                    src, dst, wpos, csr_src, GE);

    // ---- layer 1 aggregate ----
    gat_agg_l1<<<aggblocks, 512, 0, stream>>>(featb, el, er, row_ptr, csr_src, abuf);

    // ---- layer 2 (agg fuses residual + ELU + mixup + h-write) ----
    gemm_mfma<<<gblocks, 256, 0, stream>>>(abuf, wbt + WSTRIDE,
                                           featb, el, er, NP);
    gat_agg_l2<<<aggblocks, 512, 0, stream>>>(featb, el, er, row_ptr, csr_src,
                                              abuf, lamb, outh);

    // ---- logits from outh (fp32-accurate 3-product bf16 split MFMA) ----
    k_logits<<<lblocks, 256, 0, stream>>>(outh, woutb, bout, outlog);
}

// Round 11
// 385.935 us; speedup vs baseline: 1.0125x; 1.0125x over previous
//
#include <hip/hip_runtime.h>
#include <hip/hip_bf16.h>
#include <cstddef>

#define GN 50000
#define GE 800000
#define GH 4
#define GD 32
#define SLOPE 0.2f
#define LOG2E 1.4426950408889634f

typedef unsigned short ushort_t;
typedef unsigned int uint_t;
using short8 = __attribute__((ext_vector_type(8))) short;
using float4v = __attribute__((ext_vector_type(4))) float;

__device__ __forceinline__ ushort_t f2bf(float f) {
    union { float f; uint_t u; } v; v.f = f;
    uint_t r = v.u + 0x7fff + ((v.u >> 16) & 1);   // RNE
    return (ushort_t)(r >> 16);
}
__device__ __forceinline__ float bflo(uint_t u) { return __uint_as_float(u << 16); }
__device__ __forceinline__ float bfhi(uint_t u) { return __uint_as_float(u & 0xffff0000u); }
__device__ __forceinline__ float bfu(ushort_t u) { return __uint_as_float((uint_t)u << 16); }

// v_cvt_pk_bf16_f32: D[15:0]=bf16(lo), D[31:16]=bf16(hi), RNE — same rounding as f2bf
__device__ __forceinline__ uint_t cvt_pk_bf16(float lo, float hi) {
    uint_t r;
    asm("v_cvt_pk_bf16_f32 %0, %1, %2" : "=v"(r) : "v"(lo), "v"(hi));
    return r;
}

#if __has_builtin(__builtin_amdgcn_exp2f)
#define EXP2F(x) __builtin_amdgcn_exp2f(x)
#else
#define EXP2F(x) exp2f(x)
#endif

// broadcast within each 8-lane group (and_mask=0x18 keeps bits 3,4; or_mask=k)
#define SWZ_B(v, imm) __uint_as_float((uint_t)__builtin_amdgcn_ds_swizzle((int)__float_as_uint(v), (imm)))

// path-interleaved row slot: storage row a (0..2N) -> slot (path0/path1 interleaved)
__device__ __forceinline__ int slotmap(int a) {
    return (a < GN) ? (a << 1) : (((a - GN) << 1) | 1);
}

// extended-N GEMM geometry: 128 feature cols + 8 attn cols (el h0..3, er h0..3) + pad
#define NEXT 144
#define WSTRIDE (NEXT * 128)

// ---------------- CSR build (4 edges/thread: 4x memory-level parallelism) ----------------
__global__ void k_hist(const int* __restrict__ dst, int* __restrict__ deg, int E) {
    int i = (blockIdx.x * 256 + threadIdx.x) * 4;
    if (i + 3 < E) {
        int4 d = *(const int4*)&dst[i];
        atomicAdd(&deg[d.x], 1);
        atomicAdd(&deg[d.y], 1);
        atomicAdd(&deg[d.z], 1);
        atomicAdd(&deg[d.w], 1);
    } else {
        for (int k = i; k < E; k++) atomicAdd(&deg[dst[k]], 1);
    }
}

__global__ void k_scan1(const int* __restrict__ deg, int* __restrict__ row_ptr,
                        int* __restrict__ partials, int n) {
    __shared__ int s[256];
    int t = threadIdx.x;
    int i = blockIdx.x * 256 + t;
    int v = (i < n) ? deg[i] : 0;
    s[t] = v;
    __syncthreads();
    for (int off = 1; off < 256; off <<= 1) {
        int add = (t >= off) ? s[t - off] : 0;
        __syncthreads();
        s[t] += add;
        __syncthreads();
    }
    if (i < n) row_ptr[i] = s[t] - v;
    if (t == 255) partials[blockIdx.x] = s[255];
}

__global__ void k_scan2(int* __restrict__ partials, int nb) {
    __shared__ int s[256];
    int t = threadIdx.x;
    int v = (t < nb) ? partials[t] : 0;
    s[t] = v;
    __syncthreads();
    for (int off = 1; off < 256; off <<= 1) {
        int add = (t >= off) ? s[t - off] : 0;
        __syncthreads();
        s[t] += add;
        __syncthreads();
    }
    if (t < nb) partials[t] = s[t] - v;
}

__global__ void k_scan3(int* __restrict__ row_ptr, int* __restrict__ wpos,
                        const int* __restrict__ partials, int n, int E) {
    int i = blockIdx.x * 256 + threadIdx.x;
    if (i < n) {
        int rp = row_ptr[i] + partials[i >> 8];
        row_ptr[i] = rp;
        wpos[i] = rp;
        if (i == 0) row_ptr[n] = E;
    }
}

__global__ void k_fill(const int* __restrict__ src, const int* __restrict__ dst,
                       int* __restrict__ wpos, int* __restrict__ csr_src, int E) {
    int i = (blockIdx.x * 256 + threadIdx.x) * 4;
    if (i + 3 < E) {
        int4 d = *(const int4*)&dst[i];
        int4 s = *(const int4*)&src[i];
        int p0 = atomicAdd(&wpos[d.x], 1);
        int p1 = atomicAdd(&wpos[d.y], 1);
        int p2 = atomicAdd(&wpos[d.z], 1);
        int p3 = atomicAdd(&wpos[d.w], 1);
        csr_src[p0] = s.x;
        csr_src[p1] = s.y;
        csr_src[p2] = s.z;
        csr_src[p3] = s.w;
    } else {
        for (int k = i; k < E; k++) {
            int p = atomicAdd(&wpos[dst[k]], 1);
            csr_src[p] = src[k];
        }
    }
}

// ---------------- weight transpose+convert (merged, with folded attn cols) ----------------
// wbt layout [2][NEXT][128]: n<128 = W^T; n=128+h = W·al_h ×LOG2E; n=132+h = W·ar_h ×LOG2E;
// n>=136 = 0.  (el = (A·W)·al = A·(W·al) — GEMM emits el/er as extra output columns.)
__global__ void k_cvt_all(const float* __restrict__ W0, const float* __restrict__ W1,
                          const float* __restrict__ Wout,
                          const float* __restrict__ al0, const float* __restrict__ ar0,
                          const float* __restrict__ al1, const float* __restrict__ ar1,
                          ushort_t* __restrict__ wbt, ushort_t* __restrict__ woutb) {
    int t = blockIdx.x * 256 + threadIdx.x;
    if (t < 2 * WSTRIDE) {
        int m = t / WSTRIDE;
        int o = t % WSTRIDE;
        int n = o >> 7, k = o & 127;
        const float* W = m ? W1 : W0;
        float v;
        if (n < 128) {
            v = W[k * 128 + n];
        } else if (n < 136) {
            int j = n - 128;
            int h = j & 3;
            const float* a = (j < 4) ? (m ? al1 : al0) : (m ? ar1 : ar0);
            float s = 0.f;
#pragma unroll 8
            for (int d = 0; d < 32; d++) s += W[k * 128 + h * 32 + d] * a[h * 32 + d];
            v = s * LOG2E;
        } else {
            v = 0.f;
        }
        wbt[t] = f2bf(v);
    } else {
        int u = t - 2 * WSTRIDE;      // 0..6143
        if (u < 48 * 128) {
            int n = u >> 7, k = u & 127;
            float w = (n < 40) ? Wout[k * 40 + n] : 0.f;
            ushort_t h = f2bf(w);
            woutb[u] = h;
            woutb[48 * 128 + u] = f2bf(w - bfu(h));
        }
    }
}

// C-store (interleaved row layout): pack row pairs with v_cvt_pk_bf16_f32;
// 9th tile = el/er direct fp32 stores (already LOG2E-scaled by the weights).
__device__ __forceinline__ void store_c_ext(ushort_t* __restrict__ Cb,
                                            float* __restrict__ el,
                                            float* __restrict__ er,
                                            const float4v acc[2][9],
                                            int r0, int quad, int col, int M) {
#pragma unroll
    for (int rt = 0; rt < 2; rt++)
#pragma unroll
        for (int nt = 0; nt < 8; nt++) {
            int rb = r0 + rt * 16 + quad * 4;
            int c = nt * 16 + col;
            uint_t p01 = cvt_pk_bf16(acc[rt][nt][0], acc[rt][nt][1]);
            uint_t p23 = cvt_pk_bf16(acc[rt][nt][2], acc[rt][nt][3]);
            if (rb + 0 < M) Cb[(size_t)slotmap(rb + 0) * 128 + c] = (ushort_t)p01;
            if (rb + 1 < M) Cb[(size_t)slotmap(rb + 1) * 128 + c] = (ushort_t)(p01 >> 16);
            if (rb + 2 < M) Cb[(size_t)slotmap(rb + 2) * 128 + c] = (ushort_t)p23;
            if (rb + 3 < M) Cb[(size_t)slotmap(rb + 3) * 128 + c] = (ushort_t)(p23 >> 16);
        }
    // attn columns: col<4 -> el head col; col in 4..7 -> er head col-4
    if (col < 8) {
        float* dstp = (col < 4) ? el : er;
        int h = col & 3;
#pragma unroll
        for (int rt = 0; rt < 2; rt++)
#pragma unroll
            for (int r = 0; r < 4; r++) {
                int row = r0 + rt * 16 + quad * 4 + r;
                if (row < M) dstp[slotmap(row) * 4 + h] = acc[rt][8][r];
            }
    }
}

// ---------------- MFMA GEMM (fp32 A, layer 1), N=144 incl. attn cols ----------------
__global__ __launch_bounds__(256) void gemm_mfma32(const float* __restrict__ A0,
                                                   const float* __restrict__ A1,
                                                   const ushort_t* __restrict__ WbT,
                                                   ushort_t* __restrict__ Cb,
                                                   float* __restrict__ el,
                                                   float* __restrict__ er, int M) {
    __shared__ ushort_t Bs[NEXT][136];
    int tid = threadIdx.x;
    for (int i = tid; i < NEXT * 16; i += 256) {
        int n = i >> 4;
        int kc = (i & 15) << 3;
        *(short8*)&Bs[n][kc] = *(const short8*)&WbT[n * 128 + kc];
    }
    __syncthreads();
    int wid = tid >> 6, lane = tid & 63;
    int r0 = blockIdx.x * 128 + wid * 32;
    int col = lane & 15, quad = lane >> 4;
    float4v acc[2][9];
#pragma unroll
    for (int rt = 0; rt < 2; rt++)
#pragma unroll
        for (int t = 0; t < 9; t++) acc[rt][t] = (float4v){0.f, 0.f, 0.f, 0.f};
    int ar_[2] = {r0 + col, r0 + 16 + col};
    const float* Ap[2];
#pragma unroll
    for (int rt = 0; rt < 2; rt++) {
        int a = ar_[rt];
        Ap[rt] = (a < M) ? ((a < GN) ? (A0 + (size_t)a * 128)
                                     : (A1 + (size_t)(a - GN) * 128)) : nullptr;
    }
#pragma unroll
    for (int ks = 0; ks < 4; ks++) {
        short8 af[2];
#pragma unroll
        for (int rt = 0; rt < 2; rt++) {
            af[rt] = (short8){};
            if (Ap[rt]) {
                float4 v0 = *(const float4*)&Ap[rt][ks * 32 + quad * 8];
                float4 v1 = *(const float4*)&Ap[rt][ks * 32 + quad * 8 + 4];
                union { short8 s; uint_t u[4]; } cv;
                cv.u[0] = cvt_pk_bf16(v0.x, v0.y);
                cv.u[1] = cvt_pk_bf16(v0.z, v0.w);
                cv.u[2] = cvt_pk_bf16(v1.x, v1.y);
                cv.u[3] = cvt_pk_bf16(v1.z, v1.w);
                af[rt] = cv.s;
            }
        }
#pragma unroll
        for (int nt = 0; nt < 9; nt++) {
            short8 bf = *(const short8*)&Bs[nt * 16 + col][ks * 32 + quad * 8];
            acc[0][nt] = __builtin_amdgcn_mfma_f32_16x16x32_bf16(af[0], bf, acc[0][nt], 0, 0, 0);
            acc[1][nt] = __builtin_amdgcn_mfma_f32_16x16x32_bf16(af[1], bf, acc[1][nt], 0, 0, 0);
        }
    }
    store_c_ext(Cb, el, er, acc, r0, quad, col, M);
}

// ---------------- MFMA GEMM (bf16 A interleaved, layer 2), N=144 ----------------
__global__ __launch_bounds__(256) void gemm_mfma(const ushort_t* __restrict__ A,
                                                 const ushort_t* __restrict__ WbT,
                                                 ushort_t* __restrict__ Cb,
                                                 float* __restrict__ el,
                                                 float* __restrict__ er, int M) {
    __shared__ ushort_t Bs[NEXT][136];
    int tid = threadIdx.x;
    for (int i = tid; i < NEXT * 16; i += 256) {
        int n = i >> 4;
        int kc = (i & 15) << 3;
        *(short8*)&Bs[n][kc] = *(const short8*)&WbT[n * 128 + kc];
    }
    __syncthreads();
    int wid = tid >> 6, lane = tid & 63;
    int r0 = blockIdx.x * 128 + wid * 32;
    int col = lane & 15, quad = lane >> 4;
    float4v acc[2][9];
#pragma unroll
    for (int rt = 0; rt < 2; rt++)
#pragma unroll
        for (int t = 0; t < 9; t++) acc[rt][t] = (float4v){0.f, 0.f, 0.f, 0.f};
    int ar_[2] = {r0 + col, r0 + 16 + col};
    const ushort_t* Ap[2];
#pragma unroll
    for (int rt = 0; rt < 2; rt++) {
        int a = ar_[rt];
        Ap[rt] = (a < M) ? (A + (size_t)slotmap(a) * 128) : nullptr;
    }
#pragma unroll
    for (int ks = 0; ks < 4; ks++) {
        short8 af[2];
#pragma unroll
        for (int rt = 0; rt < 2; rt++) {
            af[rt] = (short8){};
            if (Ap[rt]) af[rt] = *(const short8*)&Ap[rt][ks * 32 + quad * 8];
        }
#pragma unroll
        for (int nt = 0; nt < 9; nt++) {
            short8 bf = *(const short8*)&Bs[nt * 16 + col][ks * 32 + quad * 8];
            acc[0][nt] = __builtin_amdgcn_mfma_f32_16x16x32_bf16(af[0], bf, acc[0][nt], 0, 0, 0);
            acc[1][nt] = __builtin_amdgcn_mfma_f32_16x16x32_bf16(af[1], bf, acc[1][nt], 0, 0, 0);
        }
    }
    store_c_ext(Cb, el, er, acc, r0, quad, col, M);
}

// ---- shared agg gather core (unchanged from measured-best: one node/wave,
// 16-edge masked blocks, gathered el, dedup'd exp, ds_swizzle broadcast) ----
__device__ __forceinline__ void agg_core(
    const ushort_t* __restrict__ featb, const float* __restrict__ el, float ern,
    const int* __restrict__ csr_src, int base, int deg, uint_t eo, uint_t fofs,
    int lk, float& v0, float& v1, float& v2, float& v3) {
    if (deg <= 0) { v0 = v1 = v2 = v3 = 0.f; return; }
    float a0 = 0.f, a1 = 0.f, a2 = 0.f, a3 = 0.f, ss = 0.f;
    int nblk = (deg + 15) >> 4;
    int e1 = base + deg - 1;
    int jb = base;
    int s[16], t[16];
#pragma unroll
    for (int k = 0; k < 16; k++) s[k] = csr_src[min(jb + k, e1)];
    float elA = el[(uint_t)csr_src[min(jb + lk, e1)] * 8u + eo];
    float elB = el[(uint_t)csr_src[min(jb + lk + 8, e1)] * 8u + eo];
    for (int b = 0;;) {
        int rem = deg - (b << 4);
        uint2 f[16];
#pragma unroll
        for (int k = 0; k < 16; k++)
            f[k] = *(const uint2*)&featb[(uint_t)s[k] * 256u + fofs];
        bool more = (b + 1) < nblk;
        float elA2 = 0.f, elB2 = 0.f;
        if (more) {
            int nj = jb + 16;
#pragma unroll
            for (int k = 0; k < 16; k++) t[k] = csr_src[min(nj + k, e1)];
            elA2 = el[(uint_t)csr_src[min(nj + lk, e1)] * 8u + eo];
            elB2 = el[(uint_t)csr_src[min(nj + lk + 8, e1)] * 8u + eo];
        }
        float eA = elA + ern; eA = fmaxf(eA, SLOPE * eA);
        float eB = elB + ern; eB = fmaxf(eB, SLOPE * eB);
        float wA = (lk < rem) ? EXP2F(eA) : 0.f;
        float wB = (lk + 8 < rem) ? EXP2F(eB) : 0.f;
        float wv[16];
        wv[0]  = SWZ_B(wA, 0x018); wv[1]  = SWZ_B(wA, 0x038);
        wv[2]  = SWZ_B(wA, 0x058); wv[3]  = SWZ_B(wA, 0x078);
        wv[4]  = SWZ_B(wA, 0x098); wv[5]  = SWZ_B(wA, 0x0B8);
        wv[6]  = SWZ_B(wA, 0x0D8); wv[7]  = SWZ_B(wA, 0x0F8);
        wv[8]  = SWZ_B(wB, 0x018); wv[9]  = SWZ_B(wB, 0x038);
        wv[10] = SWZ_B(wB, 0x058); wv[11] = SWZ_B(wB, 0x078);
        wv[12] = SWZ_B(wB, 0x098); wv[13] = SWZ_B(wB, 0x0B8);
        wv[14] = SWZ_B(wB, 0x0D8); wv[15] = SWZ_B(wB, 0x0F8);
#pragma unroll
        for (int k = 0; k < 16; k++) {
            float w = wv[k];
            ss += w;
            a0 += w * bflo(f[k].x);
            a1 += w * bfhi(f[k].x);
            a2 += w * bflo(f[k].y);
            a3 += w * bfhi(f[k].y);
        }
        if (!more) break;
        b++; jb += 16;
#pragma unroll
        for (int k = 0; k < 16; k++) s[k] = t[k];
        elA = elA2; elB = elB2;
    }
    float inv = 1.f / ss;
    v0 = a0 * inv; v1 = a1 * inv; v2 = a2 * inv; v3 = a3 * inv;
}

// ---------------- layer-1 aggregate: -> abuf (bf16, interleaved) ----------------
__global__ __launch_bounds__(512) void gat_agg_l1(
    const ushort_t* __restrict__ featb, const float* __restrict__ el,
    const float* __restrict__ er, const int* __restrict__ row_ptr,
    const int* __restrict__ csr_src, ushort_t* __restrict__ abuf) {
    int n = __builtin_amdgcn_readfirstlane(blockIdx.x * 8 + (threadIdx.x >> 6));
    if (n >= GN) return;
    int lane = threadIdx.x & 63;
    int half = lane >> 5;
    int q = lane & 31;
    int lk = lane & 7, q4 = q << 2;
    uint_t eo = (uint_t)(half * 4 + ((lane >> 3) & 3));
    uint_t fofs = (uint_t)(half * 128 + q4);
    float ern = er[(uint_t)n * 8u + eo];
    int base = row_ptr[n];
    int deg = row_ptr[n + 1] - base;
    float v0, v1, v2, v3;
    agg_core(featb, el, ern, csr_src, base, deg, eo, fofs, lk, v0, v1, v2, v3);
    v0 = v0 > 0.f ? v0 : __expf(v0) - 1.f;
    v1 = v1 > 0.f ? v1 : __expf(v1) - 1.f;
    v2 = v2 > 0.f ? v2 : __expf(v2) - 1.f;
    v3 = v3 > 0.f ? v3 : __expf(v3) - 1.f;
    size_t idx = ((size_t)(2 * n + half)) * 128 + q4;
    uint2 o;
    o.x = cvt_pk_bf16(v0, v1);
    o.y = cvt_pk_bf16(v2, v3);
    *(uint2*)&abuf[idx] = o;
}

// ---------------- layer-2 aggregate + residual + ELU + mixup + h write ----------------
__global__ __launch_bounds__(512) void gat_agg_l2(
    const ushort_t* __restrict__ featb, const float* __restrict__ el,
    const float* __restrict__ er, const int* __restrict__ row_ptr,
    const int* __restrict__ csr_src, const ushort_t* __restrict__ resid,
    const float* __restrict__ lamb, float* __restrict__ outh) {
    int tid = threadIdx.x;
    int n = __builtin_amdgcn_readfirstlane(blockIdx.x * 8 + (tid >> 6));
    if (n >= GN) return;
    int lane = tid & 63;
    int half = lane >> 5;
    int q = lane & 31;
    int lk = lane & 7, q4 = q << 2;
    uint_t eo = (uint_t)(half * 4 + ((lane >> 3) & 3));
    uint_t fofs = (uint_t)(half * 128 + q4);
    float ern = er[(uint_t)n * 8u + eo];
    int base = row_ptr[n];
    int deg = row_ptr[n + 1] - base;
    float v0, v1, v2, v3;
    agg_core(featb, el, ern, csr_src, base, deg, eo, fofs, lk, v0, v1, v2, v3);
    // residual (bf16, interleaved) + ELU
    size_t idx = ((size_t)(2 * n + half)) * 128 + q4;
    ushort4 r = *(const ushort4*)&resid[idx];
    v0 += bfu(r.x); v1 += bfu(r.y); v2 += bfu(r.z); v3 += bfu(r.w);
    v0 = v0 > 0.f ? v0 : __expf(v0) - 1.f;
    v1 = v1 > 0.f ? v1 : __expf(v1) - 1.f;
    v2 = v2 > 0.f ? v2 : __expf(v2) - 1.f;
    v3 = v3 > 0.f ? v3 : __expf(v3) - 1.f;
    // mixup across halves (partner lane = lane ^ 32)
    float p0 = __shfl_xor(v0, 32, 64);
    float p1 = __shfl_xor(v1, 32, 64);
    float p2 = __shfl_xor(v2, 32, 64);
    float p3 = __shfl_xor(v3, 32, 64);
    float lam = lamb[0];
    if (half == 0) {
        float m0 = lam * v0 + (1.f - lam) * p0;
        float m1 = lam * v1 + (1.f - lam) * p1;
        float m2 = lam * v2 + (1.f - lam) * p2;
        float m3 = lam * v3 + (1.f - lam) * p3;
        *(float4*)&outh[(size_t)n * 128 + q4] = make_float4(m0, m1, m2, m3);
    }
}

// ---------------- logits: H[N,128] (f32) x Wout[128,40] via 3-product bf16-split MFMA
__global__ __launch_bounds__(256) void k_logits(const float* __restrict__ Hf,
                                                const ushort_t* __restrict__ Wb,
                                                const float* __restrict__ bout,
                                                float* __restrict__ outlog) {
    __shared__ ushort_t Bh[48][136];
    __shared__ ushort_t Bl[48][136];
    int tid = threadIdx.x;
    for (int i = tid; i < 48 * 16; i += 256) {
        int n = i >> 4;
        int kc = (i & 15) << 3;
        *(short8*)&Bh[n][kc] = *(const short8*)&Wb[n * 128 + kc];
        *(short8*)&Bl[n][kc] = *(const short8*)&Wb[48 * 128 + n * 128 + kc];
    }
    __syncthreads();
    int wid = tid >> 6, lane = tid & 63;
    int r0 = blockIdx.x * 128 + wid * 32;
    int col = lane & 15, quad = lane >> 4;
    float4v acc[2][3];
#pragma unroll
    for (int rt = 0; rt < 2; rt++)
#pragma unroll
        for (int nt = 0; nt < 3; nt++) acc[rt][nt] = (float4v){0.f, 0.f, 0.f, 0.f};
    int ar_[2] = {r0 + col, r0 + 16 + col};
#pragma unroll
    for (int ks = 0; ks < 4; ks++) {
        short8 ah[2], alo[2];
#pragma unroll
        for (int rt = 0; rt < 2; rt++) {
            ah[rt] = (short8){};
            alo[rt] = (short8){};
            if (ar_[rt] < GN) {
                const float* p = Hf + (size_t)ar_[rt] * 128 + ks * 32 + quad * 8;
                float4 x = *(const float4*)p;
                float4 y = *(const float4*)(p + 4);
                union { short8 s; uint_t u[4]; } ch, cl;
                ch.u[0] = cvt_pk_bf16(x.x, x.y);
                ch.u[1] = cvt_pk_bf16(x.z, x.w);
                ch.u[2] = cvt_pk_bf16(y.x, y.y);
                ch.u[3] = cvt_pk_bf16(y.z, y.w);
                cl.u[0] = cvt_pk_bf16(x.x - bflo(ch.u[0]), x.y - bfhi(ch.u[0]));
                cl.u[1] = cvt_pk_bf16(x.z - bflo(ch.u[1]), x.w - bfhi(ch.u[1]));
                cl.u[2] = cvt_pk_bf16(y.x - bflo(ch.u[2]), y.y - bfhi(ch.u[2]));
                cl.u[3] = cvt_pk_bf16(y.z - bflo(ch.u[3]), y.w - bfhi(ch.u[3]));
                ah[rt] = ch.s;
                alo[rt] = cl.s;
            }
        }
#pragma unroll
        for (int nt = 0; nt < 3; nt++) {
            short8 bh = *(const short8*)&Bh[nt * 16 + col][ks * 32 + quad * 8];
            short8 bl = *(const short8*)&Bl[nt * 16 + col][ks * 32 + quad * 8];
#pragma unroll
            for (int rt = 0; rt < 2; rt++) {
                acc[rt][nt] = __builtin_amdgcn_mfma_f32_16x16x32_bf16(ah[rt], bh, acc[rt][nt], 0, 0, 0);
                acc[rt][nt] = __builtin_amdgcn_mfma_f32_16x16x32_bf16(alo[rt], bh, acc[rt][nt], 0, 0, 0);
                acc[rt][nt] = __builtin_amdgcn_mfma_f32_16x16x32_bf16(ah[rt], bl, acc[rt][nt], 0, 0, 0);
            }
        }
    }
#pragma unroll
    for (int nt = 0; nt < 3; nt++) {
        int c = nt * 16 + col;
        if (c < 40) {
            float bv = bout[c];
#pragma unroll
            for (int rt = 0; rt < 2; rt++)
#pragma unroll
                for (int r = 0; r < 4; r++) {
                    int row = r0 + rt * 16 + quad * 4 + r;
                    if (row < GN) outlog[(size_t)row * 40 + c] = acc[rt][nt][r] + bv;
                }
        }
    }
}

extern "C" void kernel_launch(void* const* d_in, const int* in_sizes, int n_in,
                              void* d_out, int out_size, void* d_ws, size_t ws_size,
                              hipStream_t stream) {
    const float* inputs = (const float*)d_in[0];
    const float* target = (const float*)d_in[1];
    const float* lamb   = (const float*)d_in[2];
    const float* W0     = (const float*)d_in[3];
    const float* al0    = (const float*)d_in[4];
    const float* ar0    = (const float*)d_in[5];
    const float* W1     = (const float*)d_in[6];
    const float* al1    = (const float*)d_in[7];
    const float* ar1    = (const float*)d_in[8];
    const float* Wout   = (const float*)d_in[9];
    const float* bout   = (const float*)d_in[10];
    const int*   src    = (const int*)d_in[11];
    const int*   dst    = (const int*)d_in[12];

    float* out = (float*)d_out;
    float* outh = out;                          // [N,128]
    float* outlog = out + (size_t)GN * 128;     // [N,40]

    const int NP = 2 * GN;
    // workspace layout (featb/abuf/el/er are path-INTERLEAVED: slot = 2n+half)
    ushort_t* featb = (ushort_t*)d_ws;                    // [2N,128] bf16
    ushort_t* abuf  = featb + (size_t)NP * 128;           // [2N,128] bf16 (layer1 out / resid)
    float* el = (float*)(abuf + (size_t)NP * 128);        // [2N,4]  (pre-scaled by LOG2E)
    float* er = el + (size_t)NP * GH;                     // [2N,4]  (pre-scaled by LOG2E)
    ushort_t* wbt = (ushort_t*)(er + (size_t)NP * GH);    // [2][144][128] bf16 (ext cols)
    int* row_ptr  = (int*)(wbt + 2 * WSTRIDE);            // N+1
    int* wpos     = row_ptr + (GN + 1);                   // N
    int* csr_src  = wpos + GN;                            // E (+pad)
    int* partials = csr_src + GE + 16;                    // 256
    ushort_t* woutb = (ushort_t*)(partials + 256);        // [2][48][128] bf16 hi/lo

    const int nb = (GN + 255) / 256;
    const int eb4 = (GE / 4 + 255) / 256;     // 4 edges per thread
    const int gblocks = (NP + 127) / 128;
    const int aggblocks = (GN + 7) / 8;       // one node per wave, 8 waves/block
    const int lblocks = (GN + 127) / 128;
    const int cvtblocks = (2 * WSTRIDE + 48 * 128 + 255) / 256;

    // ---- CSR build (4 edges/thread for 4x MLP) ----
    hipMemsetAsync(wpos, 0, GN * sizeof(int), stream);
    k_hist<<<eb4, 256, 0, stream>>>(dst, wpos, GE);
    k_scan1<<<nb, 256, 0, stream>>>(wpos, row_ptr, partials, GN);
    k_scan2<<<1, 256, 0, stream>>>(partials, nb);
    k_scan3<<<nb, 256, 0, stream>>>(row_ptr, wpos, partials, GN, GE);
    k_fill<<<eb4, 256, 0, stream>>>(src, dst, wpos, csr_src, GE);

    // ---- weights convert (merged; includes folded W·al / W·ar columns) ----
    k_cvt_all<<<cvtblocks, 256, 0, stream>>>(W0, W1, Wout, al0, ar0, al1, ar1,
                                             wbt, woutb);

    // ---- layer 1 (GEMM emits feat + el/er directly; agg: softmax-weight + ELU) ----
    gemm_mfma32<<<gblocks, 256, 0, stream>>>(inputs, target, wbt,
                                             featb, el, er, NP);
    gat_agg_l1<<<aggblocks, 512, 0, stream>>>(featb, el, er, row_ptr, csr_src, abuf);

    // ---- layer 2 (agg fuses residual + ELU + mixup + h-write) ----
    gemm_mfma<<<gblocks, 256, 0, stream>>>(abuf, wbt + WSTRIDE,
                                           featb, el, er, NP);
    gat_agg_l2<<<aggblocks, 512, 0, stream>>>(featb, el, er, row_ptr, csr_src,
                                              abuf, lamb, outh);

    // ---- logits from outh (fp32-accurate 3-product bf16 split MFMA) ----
    k_logits<<<lblocks, 256, 0, stream>>>(outh, woutb, bout, outlog);
}

// Round 12
// 348.759 us; speedup vs baseline: 1.1204x; 1.1066x over previous
//
#include <hip/hip_runtime.h>
#include <hip/hip_bf16.h>
#include <cstddef>

#define GN 50000
#define GE 800000
#define GH 4
#define GD 32
#define SLOPE 0.2f
#define LOG2E 1.4426950408889634f

typedef unsigned short ushort_t;
typedef unsigned int uint_t;
using short8 = __attribute__((ext_vector_type(8))) short;
using float4v = __attribute__((ext_vector_type(4))) float;

__device__ __forceinline__ ushort_t f2bf(float f) {
    union { float f; uint_t u; } v; v.f = f;
    uint_t r = v.u + 0x7fff + ((v.u >> 16) & 1);   // RNE
    return (ushort_t)(r >> 16);
}
__device__ __forceinline__ float bflo(uint_t u) { return __uint_as_float(u << 16); }
__device__ __forceinline__ float bfhi(uint_t u) { return __uint_as_float(u & 0xffff0000u); }
__device__ __forceinline__ float bfu(ushort_t u) { return __uint_as_float((uint_t)u << 16); }

// v_cvt_pk_bf16_f32: D[15:0]=bf16(lo), D[31:16]=bf16(hi), RNE — same rounding as f2bf
__device__ __forceinline__ uint_t cvt_pk_bf16(float lo, float hi) {
    uint_t r;
    asm("v_cvt_pk_bf16_f32 %0, %1, %2" : "=v"(r) : "v"(lo), "v"(hi));
    return r;
}

#if __has_builtin(__builtin_amdgcn_exp2f)
#define EXP2F(x) __builtin_amdgcn_exp2f(x)
#else
#define EXP2F(x) exp2f(x)
#endif

// broadcast within each 8-lane group (and_mask=0x18 keeps bits 3,4; or_mask=k)
#define SWZ_B(v, imm) __uint_as_float((uint_t)__builtin_amdgcn_ds_swizzle((int)__float_as_uint(v), (imm)))

// path-interleaved row slot: storage row a (0..2N) -> slot (path0/path1 interleaved)
__device__ __forceinline__ int slotmap(int a) {
    return (a < GN) ? (a << 1) : (((a - GN) << 1) | 1);
}

// extended-N GEMM geometry: 128 feature cols + 8 attn cols (el h0..3, er h0..3) + pad
#define NEXT 144
#define WSTRIDE (NEXT * 128)

// ---------------- FUSED: weight convert (blocks [0,cvtb)) + hist (rest) ----------------
// Independent chains; both LDS-free and low-VGPR so neither hurts the other's
// occupancy (round-10 lesson: never fuse the scatter with the VGPR-heavy GEMM).
// hist also records each edge's rank within its dst bucket -> fill needs NO atomics.
__global__ __launch_bounds__(256) void k_cvt_hist(
    const float* __restrict__ W0, const float* __restrict__ W1,
    const float* __restrict__ Wout,
    const float* __restrict__ al0, const float* __restrict__ ar0,
    const float* __restrict__ al1, const float* __restrict__ ar1,
    ushort_t* __restrict__ wbt, ushort_t* __restrict__ woutb,
    const int* __restrict__ dst, int* __restrict__ deg, int* __restrict__ rank,
    int cvtb, int E) {
    if ((int)blockIdx.x >= cvtb) {
        int i = ((blockIdx.x - cvtb) * 256 + threadIdx.x) * 4;
        if (i + 3 < E) {
            int4 d = *(const int4*)&dst[i];
            rank[i + 0] = atomicAdd(&deg[d.x], 1);
            rank[i + 1] = atomicAdd(&deg[d.y], 1);
            rank[i + 2] = atomicAdd(&deg[d.z], 1);
            rank[i + 3] = atomicAdd(&deg[d.w], 1);
        } else {
            for (int k = i; k < E; k++) rank[k] = atomicAdd(&deg[dst[k]], 1);
        }
        return;
    }
    // wbt layout [2][NEXT][128]: n<128 = W^T; n=128+h = W·al_h ×LOG2E;
    // n=132+h = W·ar_h ×LOG2E; n>=136 = 0.  (el = (A·W)·al = A·(W·al).)
    int t = blockIdx.x * 256 + threadIdx.x;
    if (t < 2 * WSTRIDE) {
        int m = t / WSTRIDE;
        int o = t % WSTRIDE;
        int n = o >> 7, k = o & 127;
        const float* W = m ? W1 : W0;
        float v;
        if (n < 128) {
            v = W[k * 128 + n];
        } else if (n < 136) {
            int j = n - 128;
            int h = j & 3;
            const float* a = (j < 4) ? (m ? al1 : al0) : (m ? ar1 : ar0);
            float s = 0.f;
#pragma unroll 8
            for (int d = 0; d < 32; d++) s += W[k * 128 + h * 32 + d] * a[h * 32 + d];
            v = s * LOG2E;
        } else {
            v = 0.f;
        }
        wbt[t] = f2bf(v);
    } else {
        int u = t - 2 * WSTRIDE;      // 0..6143
        if (u < 48 * 128) {
            int n = u >> 7, k = u & 127;
            float w = (n < 40) ? Wout[k * 40 + n] : 0.f;
            ushort_t h = f2bf(w);
            woutb[u] = h;
            woutb[48 * 128 + u] = f2bf(w - bfu(h));
        }
    }
}

__global__ void k_scan1(const int* __restrict__ deg, int* __restrict__ row_ptr,
                        int* __restrict__ partials, int n) {
    __shared__ int s[256];
    int t = threadIdx.x;
    int i = blockIdx.x * 256 + t;
    int v = (i < n) ? deg[i] : 0;
    s[t] = v;
    __syncthreads();
    for (int off = 1; off < 256; off <<= 1) {
        int add = (t >= off) ? s[t - off] : 0;
        __syncthreads();
        s[t] += add;
        __syncthreads();
    }
    if (i < n) row_ptr[i] = s[t] - v;
    if (t == 255) partials[blockIdx.x] = s[255];
}

__global__ void k_scan2(int* __restrict__ partials, int nb) {
    __shared__ int s[256];
    int t = threadIdx.x;
    int v = (t < nb) ? partials[t] : 0;
    s[t] = v;
    __syncthreads();
    for (int off = 1; off < 256; off <<= 1) {
        int add = (t >= off) ? s[t - off] : 0;
        __syncthreads();
        s[t] += add;
        __syncthreads();
    }
    if (t < nb) partials[t] = s[t] - v;
}

__global__ void k_scan3(int* __restrict__ row_ptr,
                        const int* __restrict__ partials, int n, int E) {
    int i = blockIdx.x * 256 + threadIdx.x;
    if (i < n) {
        row_ptr[i] += partials[i >> 8];
        if (i == 0) row_ptr[n] = E;
    }
}

// ---------------- atomic-free CSR fill: pos = row_ptr[dst] + rank ----------------
__global__ void k_fill(const int* __restrict__ src, const int* __restrict__ dst,
                       const int* __restrict__ rank, const int* __restrict__ row_ptr,
                       int* __restrict__ csr_src, int E) {
    int i = (blockIdx.x * 256 + threadIdx.x) * 4;
    if (i + 3 < E) {
        int4 d = *(const int4*)&dst[i];
        int4 s = *(const int4*)&src[i];
        int4 r = *(const int4*)&rank[i];
        csr_src[row_ptr[d.x] + r.x] = s.x;
        csr_src[row_ptr[d.y] + r.y] = s.y;
        csr_src[row_ptr[d.z] + r.z] = s.z;
        csr_src[row_ptr[d.w] + r.w] = s.w;
    } else {
        for (int k = i; k < E; k++)
            csr_src[row_ptr[dst[k]] + rank[k]] = src[k];
    }
}

// C-store (interleaved row layout): pack row pairs with v_cvt_pk_bf16_f32;
// 9th tile = el/er direct fp32 stores (already LOG2E-scaled by the weights).
__device__ __forceinline__ void store_c_ext(ushort_t* __restrict__ Cb,
                                            float* __restrict__ el,
                                            float* __restrict__ er,
                                            const float4v acc[2][9],
                                            int r0, int quad, int col, int M) {
#pragma unroll
    for (int rt = 0; rt < 2; rt++)
#pragma unroll
        for (int nt = 0; nt < 8; nt++) {
            int rb = r0 + rt * 16 + quad * 4;
            int c = nt * 16 + col;
            uint_t p01 = cvt_pk_bf16(acc[rt][nt][0], acc[rt][nt][1]);
            uint_t p23 = cvt_pk_bf16(acc[rt][nt][2], acc[rt][nt][3]);
            if (rb + 0 < M) Cb[(size_t)slotmap(rb + 0) * 128 + c] = (ushort_t)p01;
            if (rb + 1 < M) Cb[(size_t)slotmap(rb + 1) * 128 + c] = (ushort_t)(p01 >> 16);
            if (rb + 2 < M) Cb[(size_t)slotmap(rb + 2) * 128 + c] = (ushort_t)p23;
            if (rb + 3 < M) Cb[(size_t)slotmap(rb + 3) * 128 + c] = (ushort_t)(p23 >> 16);
        }
    // attn columns: col<4 -> el head col; col in 4..7 -> er head col-4
    if (col < 8) {
        float* dstp = (col < 4) ? el : er;
        int h = col & 3;
#pragma unroll
        for (int rt = 0; rt < 2; rt++)
#pragma unroll
            for (int r = 0; r < 4; r++) {
                int row = r0 + rt * 16 + quad * 4 + r;
                if (row < M) dstp[slotmap(row) * 4 + h] = acc[rt][8][r];
            }
    }
}

// ---------------- MFMA GEMM (fp32 A, layer 1), N=144 incl. attn cols ----------------
__global__ __launch_bounds__(256) void gemm_mfma32(const float* __restrict__ A0,
                                                   const float* __restrict__ A1,
                                                   const ushort_t* __restrict__ WbT,
                                                   ushort_t* __restrict__ Cb,
                                                   float* __restrict__ el,
                                                   float* __restrict__ er, int M) {
    __shared__ ushort_t Bs[NEXT][136];
    int tid = threadIdx.x;
    for (int i = tid; i < NEXT * 16; i += 256) {
        int n = i >> 4;
        int kc = (i & 15) << 3;
        *(short8*)&Bs[n][kc] = *(const short8*)&WbT[n * 128 + kc];
    }
    __syncthreads();
    int wid = tid >> 6, lane = tid & 63;
    int r0 = blockIdx.x * 128 + wid * 32;
    int col = lane & 15, quad = lane >> 4;
    float4v acc[2][9];
#pragma unroll
    for (int rt = 0; rt < 2; rt++)
#pragma unroll
        for (int t = 0; t < 9; t++) acc[rt][t] = (float4v){0.f, 0.f, 0.f, 0.f};
    int ar_[2] = {r0 + col, r0 + 16 + col};
    const float* Ap[2];
#pragma unroll
    for (int rt = 0; rt < 2; rt++) {
        int a = ar_[rt];
        Ap[rt] = (a < M) ? ((a < GN) ? (A0 + (size_t)a * 128)
                                     : (A1 + (size_t)(a - GN) * 128)) : nullptr;
    }
#pragma unroll
    for (int ks = 0; ks < 4; ks++) {
        short8 af[2];
#pragma unroll
        for (int rt = 0; rt < 2; rt++) {
            af[rt] = (short8){};
            if (Ap[rt]) {
                float4 v0 = *(const float4*)&Ap[rt][ks * 32 + quad * 8];
                float4 v1 = *(const float4*)&Ap[rt][ks * 32 + quad * 8 + 4];
                union { short8 s; uint_t u[4]; } cv;
                cv.u[0] = cvt_pk_bf16(v0.x, v0.y);
                cv.u[1] = cvt_pk_bf16(v0.z, v0.w);
                cv.u[2] = cvt_pk_bf16(v1.x, v1.y);
                cv.u[3] = cvt_pk_bf16(v1.z, v1.w);
                af[rt] = cv.s;
            }
        }
#pragma unroll
        for (int nt = 0; nt < 9; nt++) {
            short8 bf = *(const short8*)&Bs[nt * 16 + col][ks * 32 + quad * 8];
            acc[0][nt] = __builtin_amdgcn_mfma_f32_16x16x32_bf16(af[0], bf, acc[0][nt], 0, 0, 0);
            acc[1][nt] = __builtin_amdgcn_mfma_f32_16x16x32_bf16(af[1], bf, acc[1][nt], 0, 0, 0);
        }
    }
    store_c_ext(Cb, el, er, acc, r0, quad, col, M);
}

// ---------------- MFMA GEMM (bf16 A interleaved, layer 2), N=144 ----------------
__global__ __launch_bounds__(256) void gemm_mfma(const ushort_t* __restrict__ A,
                                                 const ushort_t* __restrict__ WbT,
                                                 ushort_t* __restrict__ Cb,
                                                 float* __restrict__ el,
                                                 float* __restrict__ er, int M) {
    __shared__ ushort_t Bs[NEXT][136];
    int tid = threadIdx.x;
    for (int i = tid; i < NEXT * 16; i += 256) {
        int n = i >> 4;
        int kc = (i & 15) << 3;
        *(short8*)&Bs[n][kc] = *(const short8*)&WbT[n * 128 + kc];
    }
    __syncthreads();
    int wid = tid >> 6, lane = tid & 63;
    int r0 = blockIdx.x * 128 + wid * 32;
    int col = lane & 15, quad = lane >> 4;
    float4v acc[2][9];
#pragma unroll
    for (int rt = 0; rt < 2; rt++)
#pragma unroll
        for (int t = 0; t < 9; t++) acc[rt][t] = (float4v){0.f, 0.f, 0.f, 0.f};
    int ar_[2] = {r0 + col, r0 + 16 + col};
    const ushort_t* Ap[2];
#pragma unroll
    for (int rt = 0; rt < 2; rt++) {
        int a = ar_[rt];
        Ap[rt] = (a < M) ? (A + (size_t)slotmap(a) * 128) : nullptr;
    }
#pragma unroll
    for (int ks = 0; ks < 4; ks++) {
        short8 af[2];
#pragma unroll
        for (int rt = 0; rt < 2; rt++) {
            af[rt] = (short8){};
            if (Ap[rt]) af[rt] = *(const short8*)&Ap[rt][ks * 32 + quad * 8];
        }
#pragma unroll
        for (int nt = 0; nt < 9; nt++) {
            short8 bf = *(const short8*)&Bs[nt * 16 + col][ks * 32 + quad * 8];
            acc[0][nt] = __builtin_amdgcn_mfma_f32_16x16x32_bf16(af[0], bf, acc[0][nt], 0, 0, 0);
            acc[1][nt] = __builtin_amdgcn_mfma_f32_16x16x32_bf16(af[1], bf, acc[1][nt], 0, 0, 0);
        }
    }
    store_c_ext(Cb, el, er, acc, r0, quad, col, M);
}

// ---- shared agg gather core (unchanged from measured-best: one node/wave,
// 16-edge masked blocks, gathered el, dedup'd exp, ds_swizzle broadcast) ----
__device__ __forceinline__ void agg_core(
    const ushort_t* __restrict__ featb, const float* __restrict__ el, float ern,
    const int* __restrict__ csr_src, int base, int deg, uint_t eo, uint_t fofs,
    int lk, float& v0, float& v1, float& v2, float& v3) {
    if (deg <= 0) { v0 = v1 = v2 = v3 = 0.f; return; }
    float a0 = 0.f, a1 = 0.f, a2 = 0.f, a3 = 0.f, ss = 0.f;
    int nblk = (deg + 15) >> 4;
    int e1 = base + deg - 1;
    int jb = base;
    int s[16], t[16];
#pragma unroll
    for (int k = 0; k < 16; k++) s[k] = csr_src[min(jb + k, e1)];
    float elA = el[(uint_t)csr_src[min(jb + lk, e1)] * 8u + eo];
    float elB = el[(uint_t)csr_src[min(jb + lk + 8, e1)] * 8u + eo];
    for (int b = 0;;) {
        int rem = deg - (b << 4);
        uint2 f[16];
#pragma unroll
        for (int k = 0; k < 16; k++)
            f[k] = *(const uint2*)&featb[(uint_t)s[k] * 256u + fofs];
        bool more = (b + 1) < nblk;
        float elA2 = 0.f, elB2 = 0.f;
        if (more) {
            int nj = jb + 16;
#pragma unroll
            for (int k = 0; k < 16; k++) t[k] = csr_src[min(nj + k, e1)];
            elA2 = el[(uint_t)csr_src[min(nj + lk, e1)] * 8u + eo];
            elB2 = el[(uint_t)csr_src[min(nj + lk + 8, e1)] * 8u + eo];
        }
        float eA = elA + ern; eA = fmaxf(eA, SLOPE * eA);
        float eB = elB + ern; eB = fmaxf(eB, SLOPE * eB);
        float wA = (lk < rem) ? EXP2F(eA) : 0.f;
        float wB = (lk + 8 < rem) ? EXP2F(eB) : 0.f;
        float wv[16];
        wv[0]  = SWZ_B(wA, 0x018); wv[1]  = SWZ_B(wA, 0x038);
        wv[2]  = SWZ_B(wA, 0x058); wv[3]  = SWZ_B(wA, 0x078);
        wv[4]  = SWZ_B(wA, 0x098); wv[5]  = SWZ_B(wA, 0x0B8);
        wv[6]  = SWZ_B(wA, 0x0D8); wv[7]  = SWZ_B(wA, 0x0F8);
        wv[8]  = SWZ_B(wB, 0x018); wv[9]  = SWZ_B(wB, 0x038);
        wv[10] = SWZ_B(wB, 0x058); wv[11] = SWZ_B(wB, 0x078);
        wv[12] = SWZ_B(wB, 0x098); wv[13] = SWZ_B(wB, 0x0B8);
        wv[14] = SWZ_B(wB, 0x0D8); wv[15] = SWZ_B(wB, 0x0F8);
#pragma unroll
        for (int k = 0; k < 16; k++) {
            float w = wv[k];
            ss += w;
            a0 += w * bflo(f[k].x);
            a1 += w * bfhi(f[k].x);
            a2 += w * bflo(f[k].y);
            a3 += w * bfhi(f[k].y);
        }
        if (!more) break;
        b++; jb += 16;
#pragma unroll
        for (int k = 0; k < 16; k++) s[k] = t[k];
        elA = elA2; elB = elB2;
    }
    float inv = 1.f / ss;
    v0 = a0 * inv; v1 = a1 * inv; v2 = a2 * inv; v3 = a3 * inv;
}

// ---------------- layer-1 aggregate: -> abuf (bf16, interleaved) ----------------
__global__ __launch_bounds__(512) void gat_agg_l1(
    const ushort_t* __restrict__ featb, const float* __restrict__ el,
    const float* __restrict__ er, const int* __restrict__ row_ptr,
    const int* __restrict__ csr_src, ushort_t* __restrict__ abuf) {
    int n = __builtin_amdgcn_readfirstlane(blockIdx.x * 8 + (threadIdx.x >> 6));
    if (n >= GN) return;
    int lane = threadIdx.x & 63;
    int half = lane >> 5;
    int q = lane & 31;
    int lk = lane & 7, q4 = q << 2;
    uint_t eo = (uint_t)(half * 4 + ((lane >> 3) & 3));
    uint_t fofs = (uint_t)(half * 128 + q4);
    float ern = er[(uint_t)n * 8u + eo];
    int base = row_ptr[n];
    int deg = row_ptr[n + 1] - base;
    float v0, v1, v2, v3;
    agg_core(featb, el, ern, csr_src, base, deg, eo, fofs, lk, v0, v1, v2, v3);
    v0 = v0 > 0.f ? v0 : __expf(v0) - 1.f;
    v1 = v1 > 0.f ? v1 : __expf(v1) - 1.f;
    v2 = v2 > 0.f ? v2 : __expf(v2) - 1.f;
    v3 = v3 > 0.f ? v3 : __expf(v3) - 1.f;
    size_t idx = ((size_t)(2 * n + half)) * 128 + q4;
    uint2 o;
    o.x = cvt_pk_bf16(v0, v1);
    o.y = cvt_pk_bf16(v2, v3);
    *(uint2*)&abuf[idx] = o;
}

// ---------------- layer-2 aggregate + residual + ELU + mixup + h write ----------------
__global__ __launch_bounds__(512) void gat_agg_l2(
    const ushort_t* __restrict__ featb, const float* __restrict__ el,
    const float* __restrict__ er, const int* __restrict__ row_ptr,
    const int* __restrict__ csr_src, const ushort_t* __restrict__ resid,
    const float* __restrict__ lamb, float* __restrict__ outh) {
    int tid = threadIdx.x;
    int n = __builtin_amdgcn_readfirstlane(blockIdx.x * 8 + (tid >> 6));
    if (n >= GN) return;
    int lane = tid & 63;
    int half = lane >> 5;
    int q = lane & 31;
    int lk = lane & 7, q4 = q << 2;
    uint_t eo = (uint_t)(half * 4 + ((lane >> 3) & 3));
    uint_t fofs = (uint_t)(half * 128 + q4);
    float ern = er[(uint_t)n * 8u + eo];
    int base = row_ptr[n];
    int deg = row_ptr[n + 1] - base;
    float v0, v1, v2, v3;
    agg_core(featb, el, ern, csr_src, base, deg, eo, fofs, lk, v0, v1, v2, v3);
    // residual (bf16, interleaved) + ELU
    size_t idx = ((size_t)(2 * n + half)) * 128 + q4;
    ushort4 r = *(const ushort4*)&resid[idx];
    v0 += bfu(r.x); v1 += bfu(r.y); v2 += bfu(r.z); v3 += bfu(r.w);
    v0 = v0 > 0.f ? v0 : __expf(v0) - 1.f;
    v1 = v1 > 0.f ? v1 : __expf(v1) - 1.f;
    v2 = v2 > 0.f ? v2 : __expf(v2) - 1.f;
    v3 = v3 > 0.f ? v3 : __expf(v3) - 1.f;
    // mixup across halves (partner lane = lane ^ 32)
    float p0 = __shfl_xor(v0, 32, 64);
    float p1 = __shfl_xor(v1, 32, 64);
    float p2 = __shfl_xor(v2, 32, 64);
    float p3 = __shfl_xor(v3, 32, 64);
    float lam = lamb[0];
    if (half == 0) {
        float m0 = lam * v0 + (1.f - lam) * p0;
        float m1 = lam * v1 + (1.f - lam) * p1;
        float m2 = lam * v2 + (1.f - lam) * p2;
        float m3 = lam * v3 + (1.f - lam) * p3;
        *(float4*)&outh[(size_t)n * 128 + q4] = make_float4(m0, m1, m2, m3);
    }
}

// ---------------- logits: H[N,128] (f32) x Wout[128,40] via 3-product bf16-split MFMA
__global__ __launch_bounds__(256) void k_logits(const float* __restrict__ Hf,
                                                const ushort_t* __restrict__ Wb,
                                                const float* __restrict__ bout,
                                                float* __restrict__ outlog) {
    __shared__ ushort_t Bh[48][136];
    __shared__ ushort_t Bl[48][136];
    int tid = threadIdx.x;
    for (int i = tid; i < 48 * 16; i += 256) {
        int n = i >> 4;
        int kc = (i & 15) << 3;
        *(short8*)&Bh[n][kc] = *(const short8*)&Wb[n * 128 + kc];
        *(short8*)&Bl[n][kc] = *(const short8*)&Wb[48 * 128 + n * 128 + kc];
    }
    __syncthreads();
    int wid = tid >> 6, lane = tid & 63;
    int r0 = blockIdx.x * 128 + wid * 32;
    int col = lane & 15, quad = lane >> 4;
    float4v acc[2][3];
#pragma unroll
    for (int rt = 0; rt < 2; rt++)
#pragma unroll
        for (int nt = 0; nt < 3; nt++) acc[rt][nt] = (float4v){0.f, 0.f, 0.f, 0.f};
    int ar_[2] = {r0 + col, r0 + 16 + col};
#pragma unroll
    for (int ks = 0; ks < 4; ks++) {
        short8 ah[2], alo[2];
#pragma unroll
        for (int rt = 0; rt < 2; rt++) {
            ah[rt] = (short8){};
            alo[rt] = (short8){};
            if (ar_[rt] < GN) {
                const float* p = Hf + (size_t)ar_[rt] * 128 + ks * 32 + quad * 8;
                float4 x = *(const float4*)p;
                float4 y = *(const float4*)(p + 4);
                union { short8 s; uint_t u[4]; } ch, cl;
                ch.u[0] = cvt_pk_bf16(x.x, x.y);
                ch.u[1] = cvt_pk_bf16(x.z, x.w);
                ch.u[2] = cvt_pk_bf16(y.x, y.y);
                ch.u[3] = cvt_pk_bf16(y.z, y.w);
                cl.u[0] = cvt_pk_bf16(x.x - bflo(ch.u[0]), x.y - bfhi(ch.u[0]));
                cl.u[1] = cvt_pk_bf16(x.z - bflo(ch.u[1]), x.w - bfhi(ch.u[1]));
                cl.u[2] = cvt_pk_bf16(y.x - bflo(ch.u[2]), y.y - bfhi(ch.u[2]));
                cl.u[3] = cvt_pk_bf16(y.z - bflo(ch.u[3]), y.w - bfhi(ch.u[3]));
                ah[rt] = ch.s;
                alo[rt] = cl.s;
            }
        }
#pragma unroll
        for (int nt = 0; nt < 3; nt++) {
            short8 bh = *(const short8*)&Bh[nt * 16 + col][ks * 32 + quad * 8];
            short8 bl = *(const short8*)&Bl[nt * 16 + col][ks * 32 + quad * 8];
#pragma unroll
            for (int rt = 0; rt < 2; rt++) {
                acc[rt][nt] = __builtin_amdgcn_mfma_f32_16x16x32_bf16(ah[rt], bh, acc[rt][nt], 0, 0, 0);
                acc[rt][nt] = __builtin_amdgcn_mfma_f32_16x16x32_bf16(alo[rt], bh, acc[rt][nt], 0, 0, 0);
                acc[rt][nt] = __builtin_amdgcn_mfma_f32_16x16x32_bf16(ah[rt], bl, acc[rt][nt], 0, 0, 0);
            }
        }
    }
#pragma unroll
    for (int nt = 0; nt < 3; nt++) {
        int c = nt * 16 + col;
        if (c < 40) {
            float bv = bout[c];
#pragma unroll
            for (int rt = 0; rt < 2; rt++)
#pragma unroll
                for (int r = 0; r < 4; r++) {
                    int row = r0 + rt * 16 + quad * 4 + r;
                    if (row < GN) outlog[(size_t)row * 40 + c] = acc[rt][nt][r] + bv;
                }
        }
    }
}

extern "C" void kernel_launch(void* const* d_in, const int* in_sizes, int n_in,
                              void* d_out, int out_size, void* d_ws, size_t ws_size,
                              hipStream_t stream) {
    const float* inputs = (const float*)d_in[0];
    const float* target = (const float*)d_in[1];
    const float* lamb   = (const float*)d_in[2];
    const float* W0     = (const float*)d_in[3];
    const float* al0    = (const float*)d_in[4];
    const float* ar0    = (const float*)d_in[5];
    const float* W1     = (const float*)d_in[6];
    const float* al1    = (const float*)d_in[7];
    const float* ar1    = (const float*)d_in[8];
    const float* Wout   = (const float*)d_in[9];
    const float* bout   = (const float*)d_in[10];
    const int*   src    = (const int*)d_in[11];
    const int*   dst    = (const int*)d_in[12];

    float* out = (float*)d_out;
    float* outh = out;                          // [N,128]
    float* outlog = out + (size_t)GN * 128;     // [N,40]

    const int NP = 2 * GN;
    // workspace layout (featb/abuf/el/er are path-INTERLEAVED: slot = 2n+half)
    ushort_t* featb = (ushort_t*)d_ws;                    // [2N,128] bf16
    ushort_t* abuf  = featb + (size_t)NP * 128;           // [2N,128] bf16 (layer1 out / resid)
    float* el = (float*)(abuf + (size_t)NP * 128);        // [2N,4]  (pre-scaled by LOG2E)
    float* er = el + (size_t)NP * GH;                     // [2N,4]  (pre-scaled by LOG2E)
    ushort_t* wbt = (ushort_t*)(er + (size_t)NP * GH);    // [2][144][128] bf16 (ext cols)
    int* row_ptr  = (int*)(wbt + 2 * WSTRIDE);            // N+1
    int* wpos     = row_ptr + (GN + 1);                   // N (degree counters)
    int* csr_src  = wpos + GN;                            // E (+pad)
    int* partials = csr_src + GE + 16;                    // 256
    int* rank     = partials + 256;                       // E (edge rank within dst bucket)
    ushort_t* woutb = (ushort_t*)(rank + GE + 16);        // [2][48][128] bf16 hi/lo

    const int nb = (GN + 255) / 256;
    const int eb4 = (GE / 4 + 255) / 256;     // 4 edges per thread
    const int gblocks = (NP + 127) / 128;
    const int aggblocks = (GN + 7) / 8;       // one node per wave, 8 waves/block
    const int lblocks = (GN + 127) / 128;
    const int cvtblocks = (2 * WSTRIDE + 48 * 128 + 255) / 256;

    // ---- stage 1: weight convert ∥ degree histogram (+rank) ----
    hipMemsetAsync(wpos, 0, GN * sizeof(int), stream);
    k_cvt_hist<<<cvtblocks + eb4, 256, 0, stream>>>(W0, W1, Wout, al0, ar0, al1, ar1,
                                                    wbt, woutb, dst, wpos, rank,
                                                    cvtblocks, GE);

    // ---- CSR prefix scans ----
    k_scan1<<<nb, 256, 0, stream>>>(wpos, row_ptr, partials, GN);
    k_scan2<<<1, 256, 0, stream>>>(partials, nb);
    k_scan3<<<nb, 256, 0, stream>>>(row_ptr, partials, GN, GE);

    // ---- atomic-free fill ----
    k_fill<<<eb4, 256, 0, stream>>>(src, dst, rank, row_ptr, csr_src, GE);

    // ---- layer 1 (GEMM emits feat + el/er directly; agg: softmax-weight + ELU) ----
    gemm_mfma32<<<gblocks, 256, 0, stream>>>(inputs, target, wbt,
                                             featb, el, er, NP);
    gat_agg_l1<<<aggblocks, 512, 0, stream>>>(featb, el, er, row_ptr, csr_src, abuf);

    // ---- layer 2 (agg fuses residual + ELU + mixup + h-write) ----
    gemm_mfma<<<gblocks, 256, 0, stream>>>(abuf, wbt + WSTRIDE,
                                           featb, el, er, NP);
    gat_agg_l2<<<aggblocks, 512, 0, stream>>>(featb, el, er, row_ptr, csr_src,
                                              abuf, lamb, outh);

    // ---- logits from outh (fp32-accurate 3-product bf16 split MFMA) ----
    k_logits<<<lblocks, 256, 0, stream>>>(outh, woutb, bout, outlog);
}